// Round 13
// baseline (1058.946 us; speedup 1.0000x reference)
//
#include <hip/hip_runtime.h>

// RNN: h_t = tanh(x[b,t]*W_ih + b_ih + b_hh + h_{t-1} @ W_hh^T), out = h_T @ W_out^T + b_out
// B=256 T=2048 H=256 P=24, fp32 in/out. One WG/batch (256 WGs = 256 CUs), 512 thr.
//
// Round-22: V_PK_FMA_F16 CHAINS. R12 post-mortem: busy/wave 366 cyc fits
// dot2=4cyc/wave64 (fp32-equivalent MAC rate, NOT 2x) -- the fp16 win was
// all DS/pair-add. The remaining step = 512 dot2-floor + 220 misc + 314
// barrier-locked stall. Only faster vector path: v_pk_fma_f16 (CDNA packed
// f16 = 2x fp32 rate on MI300X; expect 2cyc/wave64).
//  - Per slot: TWO 4-term f16x2 chains (accA over qa, accB over qb):
//    8 pk_mul + 48 pk_fma @2cyc = 128 cyc/wave (was 256).
//  - Exact f32 combine: fdot2(acc,(1,1),c) -- x1.0 products are lossless,
//    dot2 does the f16->f32 convert+add internally. 16 dot2 @4cyc = 64.
//    Net math 256->192 cyc/wave (-128/SIMD/step).
//  - Precision: rounding moves into f16 accumulators (4-term chains round
//    at ~0.1-0.2 magnitudes): est sigma_u ~6.5e-4/step -> absmax ~1.5e-2,
//    threshold 2.36e-2. R12 measured 7.8e-3 with sigma 2.8e-4.
// If pk_fma_f16 is secretly 4cyc: ~930us slight regression -> proves no
// fast f16 vector path on gfx950 -> R12 structure is the roofline.
// Locked-in from R12: fp16 W/h storage; 2 ds_read_b128/lane (j-outer, accA
// starts at lgkmcnt(1)); 8-slot select-free DPP butterfly
// (m={0,2,7,5,8,10,15,13}, xor8/7/2/1 = 0x128/0x141/0x4E/0xB1); lane
// finalizes row 8g+(c>>1), 2-dup same-addr write; lgkm-only barrier;
// HSTRH=24 padding; x block-prefetch; launch_bounds(512,1).

#define BB 256
#define TT 2048
#define HH 256
#define PP 24
#define HSTRH 24   // h chunk stride in HALFS: 16 data + 8 pad (48B, 16B-aligned)

typedef _Float16 half_t;
typedef _Float16 h2 __attribute__((ext_vector_type(2)));

struct alignas(16) hoct { h2 v[4]; };   // 8 halfs = one ds_read_b128

__device__ __forceinline__ int hidx16(int k) { return (k >> 4) * HSTRH + (k & 15); }

template<int CTRL>
__device__ __forceinline__ float dppadd(float dst, float src) {
    return dst + __int_as_float(__builtin_amdgcn_update_dpp(
        0, __float_as_int(src), CTRL, 0xf, 0xf, true));
}

__device__ __forceinline__ float fdot2f(h2 a, h2 b, float c) {
#if __has_builtin(__builtin_amdgcn_fdot2)
    return __builtin_amdgcn_fdot2(a, b, c, false);
#else
    return fmaf((float)a.x, (float)b.x, fmaf((float)a.y, (float)b.y, c));
#endif
}

// Packed f16 FMA: v_pk_fma_f16 (fused, single rounding per half).
__device__ __forceinline__ h2 pkfma(h2 a, h2 b, h2 c) {
    return __builtin_elementwise_fma(a, b, c);
}

// LDS-only barrier: orders the ds_write without draining vmcnt (x prefetch
// stays in flight; compiler waits vmcnt at first use).
__device__ __forceinline__ void lds_barrier() {
    asm volatile("s_waitcnt lgkmcnt(0)\n\ts_barrier" ::: "memory");
}

__global__ __launch_bounds__(512, 1)
void rnn_persist(const float* __restrict__ x,
                 const float* __restrict__ W_ih,
                 const float* __restrict__ W_hh,
                 const float* __restrict__ b_ih,
                 const float* __restrict__ b_hh,
                 const float* __restrict__ W_out,
                 const float* __restrict__ b_out,
                 float* __restrict__ out)
{
    __shared__ __align__(16) half_t hbuf[2][16 * HSTRH];   // 2 x 768 B

    const int tid = threadIdx.x;
    const int b   = blockIdx.x;
    const int c   = tid & 15;    // K-chunk 0..15 (DPP row lane)
    const int g   = tid >> 4;    // row group (rows 8g..8g+7)

    hbuf[0][hidx16(tid & 255)] = (half_t)0.f;   // h_0 = 0 (2-dup, same value)

    // Slot->row permutation for the select-free butterfly.
    const int m[8] = {0, 2, 7, 5, 8, 10, 15, 13};

    // Weights (fp16): slot s holds row 8g + ((c^m[s])>>1), cols 16c..16c+15.
    // 8 slots x 8 half2 = 64 VGPRs.
    h2 w2[8][8];
    #pragma unroll
    for (int s = 0; s < 8; ++s) {
        const int row_idx = 8 * g + ((c ^ m[s]) >> 1);
        const float* row = W_hh + row_idx * HH + 16 * c;
        #pragma unroll
        for (int j = 0; j < 8; ++j) {
            w2[s][j] = (h2){(half_t)row[2 * j], (half_t)row[2 * j + 1]};
        }
    }

    // Row this lane finalizes: o = 8g + (c>>1) (both parities agree).
    const int   o_fin = 8 * g + (c >> 1);
    const float wih   = W_ih[o_fin];
    const float cb    = b_ih[o_fin] + b_hh[o_fin];
    const int   widx  = hidx16(o_fin);

    __syncthreads();

    const half_t* hc0 = hbuf[0] + c * HSTRH;
    const half_t* hc1 = hbuf[1] + c * HSTRH;
    const float*  xb  = x + b * TT;

    const h2 ones = (h2){(half_t)1.f, (half_t)1.f};

    auto step = [&](const half_t* __restrict__ cur, half_t* __restrict__ nxt,
                    float xt) __attribute__((always_inline)) {
        const hoct* hq = (const hoct*)cur;
        // Two b128 reads back-to-back; accA chains consume qa only ->
        // pk_fmas start at lgkmcnt(1); accB chains start after qb lands.
        const hoct qa = hq[0], qb = hq[1];

        // Two 4-term packed-f16 chains per slot (accA: cols 0..7 of the
        // 16-col block; accB: cols 8..15), fused pk_fma, 2cyc/wave64.
        h2 accA[8], accB[8];
        #pragma unroll
        for (int s = 0; s < 8; ++s) accA[s] = w2[s][0] * qa.v[0];
        #pragma unroll
        for (int s = 0; s < 8; ++s) accA[s] = pkfma(w2[s][1], qa.v[1], accA[s]);
        #pragma unroll
        for (int s = 0; s < 8; ++s) accA[s] = pkfma(w2[s][2], qa.v[2], accA[s]);
        #pragma unroll
        for (int s = 0; s < 8; ++s) accA[s] = pkfma(w2[s][3], qa.v[3], accA[s]);
        #pragma unroll
        for (int s = 0; s < 8; ++s) accB[s] = w2[s][4] * qb.v[0];
        #pragma unroll
        for (int s = 0; s < 8; ++s) accB[s] = pkfma(w2[s][5], qb.v[1], accB[s]);
        #pragma unroll
        for (int s = 0; s < 8; ++s) accB[s] = pkfma(w2[s][6], qb.v[2], accB[s]);
        #pragma unroll
        for (int s = 0; s < 8; ++s) accB[s] = pkfma(w2[s][7], qb.v[3], accB[s]);

        // Exact f32 combine: fdot2(acc, (1,1), c) = f32(acc.x)+f32(acc.y)+c
        // (x1.0 products lossless; adds in f32 inside the dot unit).
        float acc[8];
        #pragma unroll
        for (int s = 0; s < 8; ++s)
            acc[s] = fdot2f(accB[s], ones, fdot2f(accA[s], ones, 0.f));

        // Select-free butterfly: 8 fused DPP adds.
        float b0 = dppadd<0x128>(acc[0], acc[4]);   // xor8 (row_ror:8)
        float b1 = dppadd<0x128>(acc[1], acc[5]);
        float b2 = dppadd<0x128>(acc[2], acc[6]);
        float b3 = dppadd<0x128>(acc[3], acc[7]);
        float c0 = dppadd<0x141>(b0, b2);           // xor7 (row_half_mirror)
        float c1 = dppadd<0x141>(b1, b3);
        float d  = dppadd<0x4E>(c0, c1);            // xor2 (quad_perm 2,3,0,1)
        float e  = dppadd<0xB1>(d, d);              // xor1 (quad_perm 1,0,3,2)

        // tanh(u) = 1 - 2/(e^{2u}+1); exp2 saturates cleanly at large |u|.
        const float u  = fmaf(xt, wih, cb) + e;
        const float p  = __builtin_amdgcn_exp2f(u * 2.8853900817779268f);
        const float th = fmaf(-2.f, __builtin_amdgcn_rcpf(p + 1.f), 1.f);
        nxt[widx] = (half_t)th;   // ds_write_b16; 2-dup same-addr, same value
        lds_barrier();            // lgkm-only: x prefetch stays in flight
    };

    // x block-prefetch: block's two float4s fetched one 8-step block ahead.
    float4 xa = *(const float4*)(xb + 0);
    float4 xc = *(const float4*)(xb + 4);
    for (int t = 0; t < TT; t += 8) {
        const int tn = (t + 8 < TT) ? (t + 8) : t;   // clamped (last block refetch)
        const float4 xa_n = *(const float4*)(xb + tn);
        const float4 xc_n = *(const float4*)(xb + tn + 4);
        step(hc0, hbuf[1], xa.x);
        step(hc1, hbuf[0], xa.y);
        step(hc0, hbuf[1], xa.z);
        step(hc1, hbuf[0], xa.w);
        step(hc0, hbuf[1], xc.x);
        step(hc1, hbuf[0], xc.y);
        step(hc0, hbuf[1], xc.z);
        step(hc1, hbuf[0], xc.w);
        xa = xa_n;
        xc = xc_n;
    }

    // Head: h_T in hbuf[0] (TT % 8 == 0). out[b,p] = b_out[p] + W_out[p,:].h_T
    if (tid < PP) {
        const float* wo = W_out + tid * HH;
        float s0 = 0.f, s1 = 0.f, s2 = 0.f, s3 = 0.f;
        #pragma unroll
        for (int h = 0; h < HH; h += 4) {
            s0 = fmaf(wo[h + 0], (float)hbuf[0][hidx16(h + 0)], s0);
            s1 = fmaf(wo[h + 1], (float)hbuf[0][hidx16(h + 1)], s1);
            s2 = fmaf(wo[h + 2], (float)hbuf[0][hidx16(h + 2)], s2);
            s3 = fmaf(wo[h + 3], (float)hbuf[0][hidx16(h + 3)], s3);
        }
        out[b * PP + tid] = b_out[tid] + (s0 + s1) + (s2 + s3);
    }
}

extern "C" void kernel_launch(void* const* d_in, const int* in_sizes, int n_in,
                              void* d_out, int out_size, void* d_ws, size_t ws_size,
                              hipStream_t stream) {
    const float* x     = (const float*)d_in[0];
    const float* W_ih  = (const float*)d_in[1];
    const float* W_hh  = (const float*)d_in[2];
    const float* b_ih  = (const float*)d_in[3];
    const float* b_hh  = (const float*)d_in[4];
    const float* W_out = (const float*)d_in[5];
    const float* b_out = (const float*)d_in[6];
    float* out = (float*)d_out;

    rnn_persist<<<BB, 512, 0, stream>>>(x, W_ih, W_hh, b_ih, b_hh, W_out, b_out, out);
}